// Round 4
// baseline (173.729 us; speedup 1.0000x reference)
//
#include <hip/hip_runtime.h>
#include <cstdint>
#include <cstddef>

// ---------------------------------------------------------------
// SparseAttention: B=2 L=4096 D=1024 H=16 HD=64 BS=64 NB=64 MAXB=11
// ---------------------------------------------------------------

#define MAXB 11
#define NT   16    // K-tiles: K=1024 / BK=64

typedef __attribute__((ext_vector_type(8))) short short8;
typedef __attribute__((ext_vector_type(4))) float f32x4;

#define MFMA16(a, b, c) __builtin_amdgcn_mfma_f32_16x16x32_bf16((a), (b), (c), 0, 0, 0)

#define QSCALE 0.18033688011112042f   // 0.125 * log2(e)
#define LOG2E  1.44269504089f

#define BAR()   asm volatile("s_barrier" ::: "memory")
#define LGKM0() asm volatile("s_waitcnt lgkmcnt(0)" ::: "memory")
#define VMC4()  asm volatile("s_waitcnt vmcnt(4)" ::: "memory")
#define VMC0()  asm volatile("s_waitcnt vmcnt(0)" ::: "memory")

__device__ __forceinline__ void vmc_imm(int n) {
  if (n >= 8)      asm volatile("s_waitcnt vmcnt(8)" ::: "memory");
  else if (n >= 6) asm volatile("s_waitcnt vmcnt(6)" ::: "memory");
  else if (n >= 2) asm volatile("s_waitcnt vmcnt(2)" ::: "memory");
  else             asm volatile("s_waitcnt vmcnt(0)" ::: "memory");
}

__device__ __forceinline__ ushort f2bf(float f) {
  uint32_t u = __float_as_uint(f);
  u += 0x7FFFu + ((u >> 16) & 1u);   // RNE
  return (ushort)(u >> 16);
}

__device__ __forceinline__ uint32_t cvt_pk_bf16(float lo, float hi) {
  uint32_t r;
  asm("v_cvt_pk_bf16_f32 %0, %1, %2" : "=v"(r) : "v"(lo), "v"(hi));
  return r;
}

__device__ __forceinline__ void gload_lds16(const ushort* g, ushort* l) {
  __builtin_amdgcn_global_load_lds((const __attribute__((address_space(1))) void*)g,
                                   (__attribute__((address_space(3))) void*)l, 16, 0, 0);
}

// ---------------- f32 -> bf16 conversion ----------------
__global__ __launch_bounds__(256) void cvt_kernel(const float* __restrict__ src,
                                                  ushort* __restrict__ dst, int n4) {
  int i = blockIdx.x * 256 + threadIdx.x;
  if (i >= n4) return;
  const float4 v = reinterpret_cast<const float4*>(src)[i];
  ushort4 o;
  o.x = f2bf(v.x); o.y = f2bf(v.y); o.z = f2bf(v.z); o.w = f2bf(v.w);
  reinterpret_cast<ushort4*>(dst)[i] = o;
}

// fused weight conversion: Wq,Wk,Wv -> Wqkv (contig), Wo -> Wob
__global__ __launch_bounds__(256) void cvt4_kernel(const float* __restrict__ wq,
                                                   const float* __restrict__ wk,
                                                   const float* __restrict__ wv,
                                                   const float* __restrict__ wo,
                                                   ushort* __restrict__ wqkv,
                                                   ushort* __restrict__ wob) {
  int i = blockIdx.x * 256 + threadIdx.x;      // 0 .. 4*262144-1
  const int part = i >> 18;
  const int j = i & 262143;
  const float* src = (part == 0) ? wq : (part == 1) ? wk : (part == 2) ? wv : wo;
  const float4 v = reinterpret_cast<const float4*>(src)[j];
  ushort4 o;
  o.x = f2bf(v.x); o.y = f2bf(v.y); o.z = f2bf(v.z); o.w = f2bf(v.w);
  if (part < 3) reinterpret_cast<ushort4*>(wqkv)[part * 262144 + j] = o;
  else          reinterpret_cast<ushort4*>(wob)[j] = o;
}

// ---------------- phase-pipelined GEMM mainloop: C = A * B^T ----------------
// BM=256, BN=128, BK=64, 512 threads = 8 waves (2M x 4N), wave tile 128x32.
// LDS 112KB: A dbuf 2x(2 halves of 128x64) [64KB], B TRIPLE buf 3x(128x64) [48KB].
// 2 phases/K-tile, 16 MFMA each. Deep prefetch: B(t+2) in ph1(t) (4-phase lead),
// A(t+1)hi-quarters ph1(t), A(t+2)lo-quarters ph2(t) (3-phase leads).
// Counted vmcnt: steady VMC(8) end-ph1, VMC(6) end-ph2 (FIFO-accounted).
#define AB_(buf,h) ((buf)*16384 + (h)*8192)   // A base, elems
#define BB_(s)     (32768 + (s)*8192)         // B base, elems (s = t%3)

__device__ __forceinline__ void gemm8_mainloop(const ushort* __restrict__ Ag,
                                               const ushort* __restrict__ Bg,
                                               int m0, int n0,
                                               ushort* smem, f32x4 acc[8][2]) {
  const int tid  = threadIdx.x;
  const int w    = tid >> 6;
  const int lane = tid & 63;
  const int g    = (lane >> 4) & 3;
  const int c    = lane & 15;
  const int wm   = w >> 2;           // 0..1
  const int wn   = w & 3;            // 0..3
  const int n5   = w * 64 + lane;    // chunk id 0..511
  const int rr   = n5 >> 3;          // 0..63
  const int jA   = (n5 & 7) ^ (rr & 7);

  // quarter q = h*2 + rowhalf: 64 rows of the 256-row A tile, 1 load/thread
  auto stageAq = [&](int t, int q) {
    const int h = q >> 1, rhalf = q & 1;
    gload_lds16(Ag + (size_t)(m0 + q * 64 + rr) * 1024 + t * 64 + jA * 8,
                smem + AB_(t & 1, h) + rhalf * 4096 + (w * 64) * 8);
  };
  auto stageB = [&](int t, int s) {   // 2 loads/thread, 128 rows
    #pragma unroll
    for (int i = 0; i < 2; ++i) {
      const int n = i * 512 + n5;
      const int rh = n >> 3;
      const int j = (n & 7) ^ (rh & 7);
      gload_lds16(Bg + (size_t)(n0 + rh) * 1024 + t * 64 + j * 8,
                  smem + BB_(s) + (i * 512 + w * 64) * 8);
    }
  };
  auto rdA = [&](int buf, int mi, int kk) -> short8 {
    const int rh = mi * 16 + c;
    const int cc = (kk * 4 + g) ^ (rh & 7);
    return *(const short8*)(smem + AB_(buf, wm) + rh * 64 + cc * 8);
  };
  auto rdB = [&](int s, int ni, int kk) -> short8 {
    const int nr = wn * 32 + ni * 16 + c;
    const int cc = (kk * 4 + g) ^ (nr & 7);
    return *(const short8*)(smem + BB_(s) + nr * 64 + cc * 8);
  };

  // prologue: B0, A0(q0,q2 lo first), B1, A1 lo quarters
  stageB(0, 0);
  stageAq(0, 0); stageAq(0, 2); stageAq(0, 1); stageAq(0, 3);
  stageB(1, 1);
  stageAq(1, 0); stageAq(1, 2);
  vmc_imm(6);     // B0 + A0(q0,q2) resident; 6 stay in flight
  BAR();

  short8 Ar[4][2], Br[2][2];
  #pragma unroll 2
  for (int t = 0; t < NT; ++t) {
    const int buf = t & 1;
    const int bs = t % 3;
    // ---- phase 1: read A-lo(t)+B(t); stage A(t+1)hi + B(t+2); MFMA lo ----
    #pragma unroll
    for (int mi = 0; mi < 4; ++mi) {
      Ar[mi][0] = rdA(buf, mi, 0);
      Ar[mi][1] = rdA(buf, mi, 1);
    }
    #pragma unroll
    for (int ni = 0; ni < 2; ++ni) {
      Br[ni][0] = rdB(bs, ni, 0);
      Br[ni][1] = rdB(bs, ni, 1);
    }
    if (t + 1 < NT) { stageAq(t + 1, 1); stageAq(t + 1, 3); }
    if (t + 2 < NT) stageB(t + 2, (t + 2) % 3);
    LGKM0();
    __builtin_amdgcn_s_setprio(1);
    #pragma unroll
    for (int mi = 0; mi < 4; ++mi)
      #pragma unroll
      for (int ni = 0; ni < 2; ++ni)
        acc[mi][ni] = MFMA16(Ar[mi][0], Br[ni][0], acc[mi][ni]);
    #pragma unroll
    for (int mi = 0; mi < 4; ++mi)
      #pragma unroll
      for (int ni = 0; ni < 2; ++ni)
        acc[mi][ni] = MFMA16(Ar[mi][1], Br[ni][1], acc[mi][ni]);
    __builtin_amdgcn_s_setprio(0);
    vmc_imm((t + 2 < NT) ? 8 : ((t + 1 < NT) ? 6 : 0));  // A(t)hi resident
    BAR();
    // ---- phase 2: read A-hi(t); stage A(t+2)lo; MFMA hi ----
    #pragma unroll
    for (int mi = 0; mi < 4; ++mi) {
      Ar[mi][0] = rdA(buf, mi + 4, 0);
      Ar[mi][1] = rdA(buf, mi + 4, 1);
    }
    if (t + 2 < NT) { stageAq(t + 2, 0); stageAq(t + 2, 2); }
    LGKM0();
    __builtin_amdgcn_s_setprio(1);
    #pragma unroll
    for (int mi = 0; mi < 4; ++mi)
      #pragma unroll
      for (int ni = 0; ni < 2; ++ni)
        acc[mi + 4][ni] = MFMA16(Ar[mi][0], Br[ni][0], acc[mi + 4][ni]);
    #pragma unroll
    for (int mi = 0; mi < 4; ++mi)
      #pragma unroll
      for (int ni = 0; ni < 2; ++ni)
        acc[mi + 4][ni] = MFMA16(Ar[mi][1], Br[ni][1], acc[mi + 4][ni]);
    __builtin_amdgcn_s_setprio(0);
    vmc_imm((t + 2 < NT) ? 6 : ((t + 1 < NT) ? 2 : 0));  // A(t+1)lo + B(t+1) resident
    BAR();
  }
}

// ---------------- GEMM1: QKV projection, scatter epilogue ----------------
__global__ __launch_bounds__(512, 2) void gemm_qkv(const ushort* __restrict__ Xb,
                                                   const ushort* __restrict__ W,
                                                   ushort* __restrict__ Qb,
                                                   ushort* __restrict__ Kb,
                                                   ushort* __restrict__ Vb) {
  __shared__ ushort smem[57344];   // 112 KB
  const int id  = blockIdx.x;                 // 768 blocks
  const int swz = (id & 7) * 96 + (id >> 3);  // XCD chunking (768%8==0)
  const int bm = swz / 24, bn = swz % 24;
  const int m0 = bm * 256, n0 = bn * 128;
  f32x4 acc[8][2] = {};
  gemm8_mainloop(Xb, W, m0, n0, smem, acc);

  const int tid = threadIdx.x;
  const int w = tid >> 6, lane = tid & 63;
  const int g = (lane >> 4) & 3, c = lane & 15;
  const int wm = w >> 2, wn = w & 3;
  #pragma unroll
  for (int mi = 0; mi < 8; ++mi) {
    #pragma unroll
    for (int ni = 0; ni < 2; ++ni) {
      const int n = n0 + wn * 32 + ni * 16 + c;
      const int part = n >> 10;
      const int h = (n >> 6) & 15;
      const int hd = n & 63;
      #pragma unroll
      for (int r = 0; r < 4; ++r) {
        const int m = m0 + wm * 128 + mi * 16 + g * 4 + r;
        const int b = m >> 12;
        const int lp = m & 4095;
        const size_t off = ((size_t)((b << 4) + h) * 4096 + lp) * 64 + hd;
        const float v = acc[mi][ni][r];
        if (part == 0)      Qb[off] = f2bf(v * QSCALE);
        else if (part == 1) Kb[off] = f2bf(v);
        else                Vb[off] = f2bf(v);
      }
    }
  }
}

// ---------------- GEMM2: output projection, f32 store ----------------
__global__ __launch_bounds__(512, 2) void gemm_out(const ushort* __restrict__ X2,
                                                   const ushort* __restrict__ W,
                                                   float* __restrict__ out) {
  __shared__ ushort smem[57344];
  const int id  = blockIdx.x;                 // 256 blocks
  const int swz = (id & 7) * 32 + (id >> 3);
  const int bm = swz / 8, bn = swz % 8;
  const int m0 = bm * 256, n0 = bn * 128;
  f32x4 acc[8][2] = {};
  gemm8_mainloop(X2, W, m0, n0, smem, acc);

  const int tid = threadIdx.x;
  const int w = tid >> 6, lane = tid & 63;
  const int g = (lane >> 4) & 3, c = lane & 15;
  const int wm = w >> 2, wn = w & 3;
  #pragma unroll
  for (int mi = 0; mi < 8; ++mi) {
    #pragma unroll
    for (int ni = 0; ni < 2; ++ni) {
      const int n = n0 + wn * 32 + ni * 16 + c;
      #pragma unroll
      for (int r = 0; r < 4; ++r) {
        const int m = m0 + wm * 128 + mi * 16 + g * 4 + r;
        out[(size_t)m * 1024 + n] = acc[mi][ni][r];
      }
    }
  }
}

// ---------------- V transpose: [B,H,L,64] -> [B,H,64,L] ----------------
__global__ __launch_bounds__(256) void transpose_v(const ushort* __restrict__ V,
                                                   ushort* __restrict__ Vt) {
  __shared__ __align__(16) ushort t[64][72];
  const int bid = blockIdx.x;
  const int bh = bid >> 6;
  const int blk = bid & 63;
  const int tid = threadIdx.x;
  const int row = tid >> 2;
  const int cg = (tid & 3) * 16;
  const ushort* src = V + ((size_t)bh * 4096 + blk * 64 + row) * 64 + cg;
  *(short8*)&t[row][cg]     = *(const short8*)src;
  *(short8*)&t[row][cg + 8] = *(const short8*)(src + 8);
  __syncthreads();
  short8 o0, o1;
  #pragma unroll
  for (int i = 0; i < 8; ++i) {
    o0[i] = (short)t[cg + i][row];
    o1[i] = (short)t[cg + 8 + i][row];
  }
  ushort* dst = Vt + ((size_t)bh * 64 + row) * 4096 + blk * 64 + cg;
  *(short8*)dst       = o0;
  *(short8*)(dst + 8) = o1;
}

// ---------------- block-sparse flash attention (dbuf K/V staging) ----------------
__global__ __launch_bounds__(256, 3) void attn_kernel(const ushort* __restrict__ Qb,
                                                      const ushort* __restrict__ Kb,
                                                      const ushort* __restrict__ Vt,
                                                      const int* __restrict__ bidx,
                                                      const float* __restrict__ slopes,
                                                      ushort* __restrict__ X2) {
  __shared__ __align__(16) ushort Ks[2][4096];   // [key][d] 64x64, chunk-swizzled
  __shared__ __align__(16) ushort Vs[2][4096];   // [d][key] 64x64, chunk-swizzled
  __shared__ __align__(16) ushort Ps[4][16][80];
  __shared__ int lst[MAXB + 1];

  const int phys = blockIdx.x;
  const int bid  = (phys & 7) * 256 + (phys >> 3);   // XCD swizzle
  const int qb = bid & 63;
  const int bh = bid >> 6;
  const int h  = bh & 15;
  const int b  = bh >> 4;
  const int tid = threadIdx.x;
  const int w = tid >> 6, lane = tid & 63;
  const int g = lane >> 4, c = lane & 15;
  const int i0 = w * 16;
  const float slope = slopes[h] * LOG2E;
  const int swz = c & 7;

  if (tid == 0) {
    int n = 0;
    #pragma unroll
    for (int m = 0; m < MAXB; ++m) {
      const int kb = bidx[qb * MAXB + m];
      if (kb >= 0) lst[n++] = kb;
    }
    lst[MAXB] = n;
  }

  // Q fragments (B-operand) straight from global; Q pre-scaled by QSCALE
  const ushort* qptr = Qb + ((size_t)bh * 4096 + qb * 64 + i0 + c) * 64 + g * 8;
  const short8 qf0 = *(const short8*)qptr;
  const short8 qf1 = *(const short8*)(qptr + 32);

  __syncthreads();
  const int nv = lst[MAXB];

  auto stage = [&](int kb, int bufi) {
    #pragma unroll
    for (int j = 0; j < 2; ++j) {
      const int n = w * 128 + j * 64 + lane;
      const int row = n >> 3;
      const int sc = ((n & 7) ^ (row & 7)) * 8;
      gload_lds16(Kb + ((size_t)bh * 4096 + kb * 64 + row) * 64 + sc,
                  &Ks[bufi][0] + (w * 128 + j * 64) * 8);
      gload_lds16(Vt + ((size_t)bh * 64 + row) * 4096 + kb * 64 + sc,
                  &Vs[bufi][0] + (w * 128 + j * 64) * 8);
    }
  };

  stage(lst[0], 0);

  f32x4 accO[4] = {};
  float mrun = -3e38f, lrun = 0.f;
  const int qi = qb * 64 + i0 + c;

  for (int i = 0; i < nv; ++i) {
    const int kb = lst[i];
    if (i + 1 < nv) { stage(lst[i + 1], (i + 1) & 1); VMC4(); }
    else            { VMC0(); }
    BAR();                                // tile i resident for all waves
    const ushort* Kt = &Ks[i & 1][0];
    const ushort* Vv = &Vs[i & 1][0];

    f32x4 s[4];
    #pragma unroll
    for (int ni = 0; ni < 4; ++ni) {
      f32x4 z = {};
      const ushort* kr = Kt + (ni * 16 + c) * 64;
      z = MFMA16(*(const short8*)(kr + (g ^ swz) * 8), qf0, z);
      z = MFMA16(*(const short8*)(kr + ((4 + g) ^ swz) * 8), qf1, z);
      s[ni] = z;
    }

    float mx = -3e38f;
    const int ib0 = qi - kb * 64 - g * 4;
    #pragma unroll
    for (int ni = 0; ni < 4; ++ni) {
      const float base = (float)(ib0 - ni * 16);
      #pragma unroll
      for (int r = 0; r < 4; ++r) {
        const float val = fmaf(-slope, fabsf(base - (float)r), s[ni][r]);
        s[ni][r] = val;
        mx = fmaxf(mx, val);
      }
    }
    mx = fmaxf(mx, __shfl_xor(mx, 16));
    mx = fmaxf(mx, __shfl_xor(mx, 32));
    const float mnew = fmaxf(mrun, mx);
    const float sf = __builtin_amdgcn_exp2f(mrun - mnew);
    mrun = mnew;
    float lsum = 0.f;
    #pragma unroll
    for (int ni = 0; ni < 4; ++ni)
      #pragma unroll
      for (int r = 0; r < 4; ++r) {
        const float pv = __builtin_amdgcn_exp2f(s[ni][r] - mnew);
        s[ni][r] = pv;
        lsum += pv;
      }
    lsum += __shfl_xor(lsum, 16);
    lsum += __shfl_xor(lsum, 32);
    lrun = lrun * sf + lsum;
    #pragma unroll
    for (int di = 0; di < 4; ++di)
      #pragma unroll
      for (int r = 0; r < 4; ++r)
        accO[di][r] *= sf;

    #pragma unroll
    for (int ni = 0; ni < 4; ++ni) {
      uint2 pk;
      pk.x = cvt_pk_bf16(s[ni][0], s[ni][1]);
      pk.y = cvt_pk_bf16(s[ni][2], s[ni][3]);
      *(uint2*)&Ps[w][c][ni * 16 + g * 4] = pk;
    }
    asm volatile("s_waitcnt lgkmcnt(0)" ::: "memory");
    __builtin_amdgcn_sched_barrier(0);
    const short8 pf0 = *(const short8*)&Ps[w][c][g * 8];
    const short8 pf1 = *(const short8*)&Ps[w][c][32 + g * 8];

    #pragma unroll
    for (int di = 0; di < 4; ++di) {
      const ushort* vr = Vv + (di * 16 + c) * 64;
      accO[di] = MFMA16(*(const short8*)(vr + (g ^ swz) * 8), pf0, accO[di]);
      accO[di] = MFMA16(*(const short8*)(vr + ((4 + g) ^ swz) * 8), pf1, accO[di]);
    }
    BAR();                                // readers of buf i&1 done -> reusable
  }

  const float rl = __builtin_amdgcn_rcpf(lrun);
  const size_t orow = (size_t)b * 4096 + qb * 64 + i0 + c;
  #pragma unroll
  for (int di = 0; di < 4; ++di) {
    uint2 pk;
    pk.x = cvt_pk_bf16(accO[di][0] * rl, accO[di][1] * rl);
    pk.y = cvt_pk_bf16(accO[di][2] * rl, accO[di][3] * rl);
    *(uint2*)&X2[orow * 1024 + h * 64 + di * 16 + g * 4] = pk;
  }
}

// ---------------- launch ----------------
extern "C" void kernel_launch(void* const* d_in, const int* in_sizes, int n_in,
                              void* d_out, int out_size, void* d_ws, size_t ws_size,
                              hipStream_t stream) {
  (void)in_sizes; (void)n_in; (void)out_size; (void)ws_size;
  const float* hs     = (const float*)d_in[0];
  const float* Wq     = (const float*)d_in[1];
  const float* Wk     = (const float*)d_in[2];
  const float* Wv     = (const float*)d_in[3];
  const float* Wo     = (const float*)d_in[4];
  const float* slopes = (const float*)d_in[5];
  const int*   bidx   = (const int*)d_in[6];
  float* out = (float*)d_out;

  char* ws = (char*)d_ws;
  ushort* Xb   = (ushort*)(ws + 0);             // 16 MB (aliased by Vt later)
  ushort* Wqkv = (ushort*)(ws + 16777216);      //  6 MB
  ushort* Wob  = (ushort*)(ws + 23068672);      //  2 MB
  ushort* Qb   = (ushort*)(ws + 25165824);      // 16 MB
  ushort* Kb   = (ushort*)(ws + 41943040);      // 16 MB
  ushort* Vb   = (ushort*)(ws + 58720256);      // 16 MB (aliased by X2 later)
  ushort* Vt   = Xb;
  ushort* X2   = Vb;

  cvt_kernel<<<8192, 256, 0, stream>>>(hs, Xb, 2097152);
  cvt4_kernel<<<4096, 256, 0, stream>>>(Wq, Wk, Wv, Wo, Wqkv, Wob);

  gemm_qkv<<<768, 512, 0, stream>>>(Xb, Wqkv, Qb, Kb, Vb);
  transpose_v<<<2048, 256, 0, stream>>>(Vb, Vt);
  attn_kernel<<<2048, 256, 0, stream>>>(Qb, Kb, Vt, bidx, slopes, X2);
  gemm_out<<<256, 512, 0, stream>>>(X2, Wob, out);
}